// Round 1
// 881.520 us; speedup vs baseline: 2.4765x; 2.4765x over previous
//
#include <hip/hip_runtime.h>
#include <hip/hip_bf16.h>

// Problem constants
#define NB 64    // batch
#define TT 512   // timesteps
#define HH 512   // hidden
#define DD 512   // input dim

typedef __attribute__((ext_vector_type(8))) __bf16 bf16x8;
typedef __attribute__((ext_vector_type(4))) float f32x4;

__device__ __forceinline__ unsigned short f2bf_rn(float f) {
    union { float f; unsigned u; } v; v.f = f;
    unsigned r = v.u + 0x7FFFu + ((v.u >> 16) & 1u);
    return (unsigned short)(r >> 16);
}
__device__ __forceinline__ float bf2f(unsigned short s) {
    union { unsigned u; float f; } v; v.u = ((unsigned)s) << 16;
    return v.f;
}

// ---------------------------------------------------------------------------
// Kernel 1: Wt[n][k]   = bf16_hi(Wx[k][n])   (n in [0,512), k in [0,512))
//           Wt[n][512+k] = bf16_lo(Wx[k][n])
// Transposed + hi/lo split so the GEMM gets B^T layout with contiguous k.
// Grid: 64 blocks (8x8 tiles of 64x64), 256 threads.
// ---------------------------------------------------------------------------
__global__ __launch_bounds__(256) void wt_kernel(const float* __restrict__ Wx,
                                                 unsigned short* __restrict__ Wt) {
    const int bk = blockIdx.x >> 3, bn = blockIdx.x & 7;
    const int k0 = bk * 64, n0 = bn * 64;
    __shared__ float tile[64][65];
    const int t = threadIdx.x;
    const int kr = t >> 2, seg = t & 3;
    // coalesced read of Wx tile (16 floats / thread)
    const float4* src = (const float4*)&Wx[(k0 + kr) * HH + n0 + seg * 16];
    float4 a = src[0], b = src[1], c = src[2], d = src[3];
    float vv[16];
    *(float4*)&vv[0] = a; *(float4*)&vv[4] = b; *(float4*)&vv[8] = c; *(float4*)&vv[12] = d;
#pragma unroll
    for (int q = 0; q < 16; ++q) tile[kr][seg * 16 + q] = vv[q];
    __syncthreads();
    // write transposed, split hi/lo (16 k's of one n per thread)
    const int nr = t >> 2;
    unsigned hu[8], lu[8];
#pragma unroll
    for (int i = 0; i < 8; ++i) {
        float f0 = tile[seg * 16 + 2 * i + 0][nr];
        float f1 = tile[seg * 16 + 2 * i + 1][nr];
        unsigned short h0 = f2bf_rn(f0); unsigned short l0 = f2bf_rn(f0 - bf2f(h0));
        unsigned short h1 = f2bf_rn(f1); unsigned short l1 = f2bf_rn(f1 - bf2f(h1));
        hu[i] = (unsigned)h0 | ((unsigned)h1 << 16);
        lu[i] = (unsigned)l0 | ((unsigned)l1 << 16);
    }
    unsigned short* dh = &Wt[(n0 + nr) * 1024 + k0 + seg * 16];
    unsigned short* dl = dh + 512;
    ((uint4*)dh)[0] = make_uint4(hu[0], hu[1], hu[2], hu[3]);
    ((uint4*)dh)[1] = make_uint4(hu[4], hu[5], hu[6], hu[7]);
    ((uint4*)dl)[0] = make_uint4(lu[0], lu[1], lu[2], lu[3]);
    ((uint4*)dl)[1] = make_uint4(lu[4], lu[5], lu[6], lu[7]);
}

// ---------------------------------------------------------------------------
// Kernel 2: projection GEMM  out[i][j] = sum_k x[i][k]*Wx[k][j] + b[j]
// i in [0, 32768) (= n*T + t), split-bf16: hi*hi + hi*lo + lo*hi via MFMA.
// 64x64 tile / block, 256 threads (4 waves, each 32x32), BK=64, 8 k-chunks.
// ---------------------------------------------------------------------------
#define LDA 72  // padded LDS row stride (bf16 elems); 144 B, 16B aligned, 2-way banks
__global__ __launch_bounds__(256) void proj_kernel(const float* __restrict__ x,
                                                   const unsigned short* __restrict__ Wt,
                                                   const float* __restrict__ bias,
                                                   float* __restrict__ out) {
    __shared__ __align__(16) unsigned short a_hi[64 * LDA];
    __shared__ __align__(16) unsigned short a_lo[64 * LDA];
    __shared__ __align__(16) unsigned short b_hi[64 * LDA];
    __shared__ __align__(16) unsigned short b_lo[64 * LDA];

    const int bx = blockIdx.x;
    const int i0 = (bx >> 3) * 64;   // M tile
    const int n0 = (bx & 7) * 64;    // N tile
    const int t = threadIdx.x;
    const int row = t >> 2, seg = t & 3;       // staging: 16 elems/thread
    const int lane = t & 63, wid = t >> 6;
    const int wm = (wid >> 1) * 32, wn = (wid & 1) * 32;
    const int fr = lane & 15;

    f32x4 acc00 = {0.f, 0.f, 0.f, 0.f}, acc01 = acc00, acc10 = acc00, acc11 = acc00;

    for (int kc = 0; kc < 8; ++kc) {
        __syncthreads();
        // ---- stage A (convert fp32 -> hi/lo bf16) ----
        {
            const float4* src = (const float4*)&x[(i0 + row) * DD + kc * 64 + seg * 16];
            float4 a = src[0], b = src[1], c = src[2], d = src[3];
            float vv[16];
            *(float4*)&vv[0] = a; *(float4*)&vv[4] = b; *(float4*)&vv[8] = c; *(float4*)&vv[12] = d;
            unsigned hu[8], lu[8];
#pragma unroll
            for (int i = 0; i < 8; ++i) {
                unsigned short h0 = f2bf_rn(vv[2 * i]); unsigned short l0 = f2bf_rn(vv[2 * i] - bf2f(h0));
                unsigned short h1 = f2bf_rn(vv[2 * i + 1]); unsigned short l1 = f2bf_rn(vv[2 * i + 1] - bf2f(h1));
                hu[i] = (unsigned)h0 | ((unsigned)h1 << 16);
                lu[i] = (unsigned)l0 | ((unsigned)l1 << 16);
            }
            uint4* dh = (uint4*)&a_hi[row * LDA + seg * 16];
            uint4* dl = (uint4*)&a_lo[row * LDA + seg * 16];
            dh[0] = make_uint4(hu[0], hu[1], hu[2], hu[3]);
            dh[1] = make_uint4(hu[4], hu[5], hu[6], hu[7]);
            dl[0] = make_uint4(lu[0], lu[1], lu[2], lu[3]);
            dl[1] = make_uint4(lu[4], lu[5], lu[6], lu[7]);
        }
        // ---- stage B (already bf16 hi/lo in Wt) ----
        {
            const uint4* sh = (const uint4*)&Wt[(n0 + row) * 1024 + kc * 64 + seg * 16];
            const uint4* sl = (const uint4*)&Wt[(n0 + row) * 1024 + 512 + kc * 64 + seg * 16];
            uint4 h0v = sh[0], h1v = sh[1], l0v = sl[0], l1v = sl[1];
            uint4* dh = (uint4*)&b_hi[row * LDA + seg * 16];
            uint4* dl = (uint4*)&b_lo[row * LDA + seg * 16];
            dh[0] = h0v; dh[1] = h1v; dl[0] = l0v; dl[1] = l1v;
        }
        __syncthreads();
        // ---- MFMA: 3 split-combos, 2x2 tiles, 2 k32-steps ----
#pragma unroll
        for (int s = 0; s < 2; ++s) {
            const int ko = s * 32 + (lane >> 4) * 8;
            bf16x8 ah0 = *(const bf16x8*)&a_hi[(wm + fr) * LDA + ko];
            bf16x8 ah1 = *(const bf16x8*)&a_hi[(wm + 16 + fr) * LDA + ko];
            bf16x8 al0 = *(const bf16x8*)&a_lo[(wm + fr) * LDA + ko];
            bf16x8 al1 = *(const bf16x8*)&a_lo[(wm + 16 + fr) * LDA + ko];
            bf16x8 bh0 = *(const bf16x8*)&b_hi[(wn + fr) * LDA + ko];
            bf16x8 bh1 = *(const bf16x8*)&b_hi[(wn + 16 + fr) * LDA + ko];
            bf16x8 bl0 = *(const bf16x8*)&b_lo[(wn + fr) * LDA + ko];
            bf16x8 bl1 = *(const bf16x8*)&b_lo[(wn + 16 + fr) * LDA + ko];
            acc00 = __builtin_amdgcn_mfma_f32_16x16x32_bf16(ah0, bh0, acc00, 0, 0, 0);
            acc00 = __builtin_amdgcn_mfma_f32_16x16x32_bf16(ah0, bl0, acc00, 0, 0, 0);
            acc00 = __builtin_amdgcn_mfma_f32_16x16x32_bf16(al0, bh0, acc00, 0, 0, 0);
            acc01 = __builtin_amdgcn_mfma_f32_16x16x32_bf16(ah0, bh1, acc01, 0, 0, 0);
            acc01 = __builtin_amdgcn_mfma_f32_16x16x32_bf16(ah0, bl1, acc01, 0, 0, 0);
            acc01 = __builtin_amdgcn_mfma_f32_16x16x32_bf16(al0, bh1, acc01, 0, 0, 0);
            acc10 = __builtin_amdgcn_mfma_f32_16x16x32_bf16(ah1, bh0, acc10, 0, 0, 0);
            acc10 = __builtin_amdgcn_mfma_f32_16x16x32_bf16(ah1, bl0, acc10, 0, 0, 0);
            acc10 = __builtin_amdgcn_mfma_f32_16x16x32_bf16(al1, bh0, acc10, 0, 0, 0);
            acc11 = __builtin_amdgcn_mfma_f32_16x16x32_bf16(ah1, bh1, acc11, 0, 0, 0);
            acc11 = __builtin_amdgcn_mfma_f32_16x16x32_bf16(ah1, bl1, acc11, 0, 0, 0);
            acc11 = __builtin_amdgcn_mfma_f32_16x16x32_bf16(al1, bh1, acc11, 0, 0, 0);
        }
    }
    // ---- epilogue: D layout col=lane&15, row=(lane>>4)*4+r ----
    const float bc0 = bias[n0 + wn + fr];
    const float bc1 = bias[n0 + wn + 16 + fr];
#pragma unroll
    for (int r = 0; r < 4; ++r) {
        int rw0 = i0 + wm + (lane >> 4) * 4 + r;
        int rw1 = rw0 + 16;
        out[rw0 * HH + n0 + wn + fr]      = acc00[r] + bc0;
        out[rw0 * HH + n0 + wn + 16 + fr] = acc01[r] + bc1;
        out[rw1 * HH + n0 + wn + fr]      = acc10[r] + bc0;
        out[rw1 * HH + n0 + wn + 16 + fr] = acc11[r] + bc1;
    }
}

// ---------------------------------------------------------------------------
// Kernel 3: recurrence. grid 256 blocks x 512 threads, 1 block/CU.
// block b: batch g = b & 63, column slice s = b >> 6 (cols [s*128, s*128+128)).
// thread: jl = tid&127 (local col), kg = tid>>7 (k-quarter). Holds 128 fp32 of
// Wh in registers.
//
// Sync redesign vs previous version: h values are exchanged as SINGLE 64-bit
// words packing {tag = t+1, fp32 h}. One relaxed agent-scope 8B atomic store
// per element; consumers (all 384 remote threads in parallel) spin on the tag
// of their own element. Single-copy atomicity of the aligned 8B word makes
// the payload valid the instant the tag matches: no release fence, no
// vmcnt(0) drain, no flag RMW, no single-thread poll + broadcast barrier.
// Double-buffer by t&1; exact tag match + 2-step separation => no stale reads.
// Locally produced slice is published straight into LDS (never re-read via
// LLC). 2 barriers per step (was 3).
// ---------------------------------------------------------------------------
__global__ __launch_bounds__(512, 2) void rec_kernel(const float* __restrict__ h0,
                                                     const float* __restrict__ Wh,
                                                     float* __restrict__ out,
                                                     unsigned long long* __restrict__ hbuf2) {
    const int b = blockIdx.x;
    const int g = b & 63;        // batch row
    const int s = b >> 6;        // col slice
    const int c0 = s * 128;
    const int tid = threadIdx.x;
    const int jl = tid & 127;
    const int kg = tid >> 7;
    const int kb = kg * 128;
    const int j = c0 + jl;

    // Wh quarter into registers (coalesced: consecutive lanes -> consecutive j)
    float w[128];
#pragma unroll
    for (int r = 0; r < 128; ++r) w[r] = Wh[(kb + r) * HH + j];

    __shared__ float hs[HH];
    __shared__ float red[3][128];

    // software-pipelined xwx load (only kg==0 uses it)
    float xw = (kg == 0) ? out[(g * TT + 0) * HH + j] : 0.f;

#pragma unroll 1
    for (int t = 0; t < TT; ++t) {
        // obtain h_{t-1} into LDS
        if (t == 0) {
            hs[tid] = h0[g * HH + tid];
        } else if (tid < c0 || tid >= c0 + 128) {
            // remote element: poll tagged 64-bit word until tag == t
            const unsigned long long* slot =
                &hbuf2[(((unsigned)(t + 1)) & 1u) * (NB * HH) + g * HH + tid];
            unsigned long long v;
            do {
                v = __hip_atomic_load(slot, __ATOMIC_RELAXED, __HIP_MEMORY_SCOPE_AGENT);
            } while ((unsigned)(v >> 32) != (unsigned)t);
            hs[tid] = __uint_as_float((unsigned)v);
        }
        // (local elements hs[c0..c0+128) were written by kg==0 last iteration)
        __syncthreads();

        // partial matvec over this thread's k-quarter (broadcast LDS reads),
        // 4 independent accumulators -> ~128cy dependency chain instead of 512
        float p0 = 0.f, p1 = 0.f, p2 = 0.f, p3 = 0.f;
        const float4* h4 = (const float4*)&hs[kb];
#pragma unroll
        for (int r4 = 0; r4 < 32; ++r4) {
            float4 hv = h4[r4];
            p0 = fmaf(w[4 * r4 + 0], hv.x, p0);
            p1 = fmaf(w[4 * r4 + 1], hv.y, p1);
            p2 = fmaf(w[4 * r4 + 2], hv.z, p2);
            p3 = fmaf(w[4 * r4 + 3], hv.w, p3);
        }
        float p = (p0 + p1) + (p2 + p3);

        if (kg) red[kg - 1][jl] = p;
        __syncthreads();
        if (kg == 0) {
            float v = p + red[0][jl] + red[1][jl] + red[2][jl] + xw;
            // tanh via exp: exact at saturation, ~1e-7 rel error
            float hn = 1.f - 2.f / (__expf(2.f * v) + 1.f);
            // publish to remote consumers FIRST (critical path): tag = t+1
            unsigned long long pv =
                (((unsigned long long)(unsigned)(t + 1)) << 32) |
                (unsigned long long)__float_as_uint(hn);
            __hip_atomic_store(&hbuf2[((unsigned)t & 1u) * (NB * HH) + g * HH + j], pv,
                               __ATOMIC_RELAXED, __HIP_MEMORY_SCOPE_AGENT);
            hs[j] = hn;                       // local publish for next iteration
            out[(g * TT + t) * HH + j] = hn;  // overwrite xwx with h
            // prefetch next step's xwx while everyone polls
            if (t + 1 < TT) xw = out[(g * TT + t + 1) * HH + j];
        }
        // no third barrier: next sync1 orders red[] reuse and hs[] writes
    }
}

// ---------------------------------------------------------------------------
extern "C" void kernel_launch(void* const* d_in, const int* in_sizes, int n_in,
                              void* d_out, int out_size, void* d_ws, size_t ws_size,
                              hipStream_t stream) {
    (void)in_sizes; (void)n_in; (void)out_size; (void)ws_size;
    const float* x  = (const float*)d_in[0];
    const float* h0 = (const float*)d_in[1];
    const float* Wx = (const float*)d_in[2];
    const float* Wh = (const float*)d_in[3];
    const float* bv = (const float*)d_in[4];
    float* out = (float*)d_out;

    // workspace layout
    unsigned long long* hbuf2 = (unsigned long long*)d_ws;            // 2*64*512*8 = 512 KiB
    unsigned short* Wt = (unsigned short*)((char*)d_ws + 2 * NB * HH * sizeof(unsigned long long)); // 1 MiB

    // zero the tag words (tag 0 never matches t>=1; also guards against
    // stale tags from a previous timed iteration if ws is not re-poisoned)
    hipMemsetAsync(hbuf2, 0, 2 * NB * HH * sizeof(unsigned long long), stream);

    // 1) split+transpose Wx -> Wt (bf16 hi|lo, B^T layout)
    wt_kernel<<<64, 256, 0, stream>>>(Wx, Wt);

    // 2) projection GEMM: d_out = x @ Wx + b  (split-bf16 MFMA, fp32-accurate)
    proj_kernel<<<(32768 / 64) * (HH / 64), 256, 0, stream>>>(x, Wt, bv, out);

    // 3) sequential recurrence, in-place on d_out
    rec_kernel<<<NB * 4, 512, 0, stream>>>(h0, Wh, out, hbuf2);
}